// Round 3
// baseline (1290.884 us; speedup 1.0000x reference)
//
#include <hip/hip_runtime.h>

#define N_NODES 200000
#define N_EDGES 6400000
#define HID 200
#define NREP 8                    // scatter accumulator replicas (one per XCD)
#define MT 64                     // nodes per block (3125 * 64 = 200000 exactly)
#define ASTR 236                  // act row stride (fp16): 472 B -> A-frag b128 reads
                                  // land 8/bank uniform (conflict-free; 118 dw = +22 banks/row)

// Packed B layout (same as R2; now read DIRECT global->register):
// g_wph[l][tile 13][ks 7][lane 64][j 8], value = W^T[n=tile*16+(lane&15)]
//                                              [k=ks*32+(lane>>4)*8+j]
// => per-wave fragment = 1024 CONTIGUOUS bytes (perfect coalescing).
#define TILE_ELEMS (7 * 512)      // 3584 elems = 7168 B per 16-col tile
#define PL_ELEMS (13 * TILE_ELEMS)// 46592 elems per layer

// LDS: act [0, 30208) ; h0s [30208, 30464). 4 blocks/CU (VGPR-capped at 128).
#define LDS_H0S  30208
#define LDS_TOTAL 30464

typedef float f32x4 __attribute__((ext_vector_type(4)));
typedef _Float16 f16x8 __attribute__((ext_vector_type(8)));
typedef unsigned short u16;
typedef unsigned int u32;

__device__ __align__(16) float g_agg[NREP * N_NODES];
__device__ __align__(16) float g_xf8[NREP * N_NODES];    // fp32 x, replicated per XCD
__device__ __align__(16) float g_wf[6 * HID * HID];      // fp32 (VALU fallback)
__device__ __align__(16) _Float16 g_wph[6 * PL_ELEMS];   // fp16 packed W^T
__device__ int g_isbf;

__device__ __forceinline__ float bf2f(u16 u) {
  union { u32 i; float f; } v; v.i = ((u32)u) << 16; return v.f;
}
__device__ __forceinline__ u16 f2bf(float f) {  // RNE
  u32 i = __float_as_uint(f);
  return (u16)((i + 0x7FFFu + ((i >> 16) & 1u)) >> 16);
}
__device__ __forceinline__ float ldf(const void* p, int i, int isbf) {
  return isbf ? bf2f(((const u16*)p)[i]) : ((const float*)p)[i];
}

// ---- rank-2 MFMA layout self-test (fp16), reference folded at compile time ----
constexpr int tf1(int m) { return (m & 3) + 1; }
constexpr int tf2(int m) { return ((m >> 2) & 3) + 2; }
constexpr int tg1(int k) { return (k & 7) + 1; }
constexpr int tg2(int k) { return ((k >> 3) & 3) + 1; }
constexpr int tu1(int k) { return ((k * 3) & 7) + 1; }
constexpr int tu2(int k) { return ((k >> 2) & 3) + 2; }
constexpr int tw1(int n) { return ((n * 5) & 7) + 1; }
constexpr int tw2(int n) { return ((n >> 2) & 3) + 1; }
constexpr int calcS(int i, int j) {
  int s = 0;
  for (int k = 0; k < 32; ++k)
    s += (i ? tg2(k) : tg1(k)) * (j ? tu2(k) : tu1(k));
  return s;
}
__device__ __forceinline__ float refD(int m, int n) {
  constexpr int S11 = calcS(0, 0), S12 = calcS(0, 1), S21 = calcS(1, 0), S22 = calcS(1, 1);
  return (float)(tf1(m) * tw1(n) * S11 + tf1(m) * tw2(n) * S12 +
                 tf2(m) * tw1(n) * S21 + tf2(m) * tw2(n) * S22);
}
__device__ int mfma_selftest(int l15, int q) {
  f16x8 av, bv;
#pragma unroll
  for (int j = 0; j < 8; ++j) {
    int k = q * 8 + j;
    av[j] = (_Float16)(float)(tf1(l15) * tg1(k) + tf2(l15) * tg2(k));
    bv[j] = (_Float16)(float)(tu1(k) * tw1(l15) + tu2(k) * tw2(l15));
  }
  f32x4 d = __builtin_amdgcn_mfma_f32_16x16x32_f16(av, bv, (f32x4){0.f, 0.f, 0.f, 0.f}, 0, 0, 0);
  bool ok0 = true, ok1 = true;
#pragma unroll
  for (int r = 0; r < 4; ++r) {
    ok0 = ok0 && (d[r] == refD(q * 4 + r, l15));
    ok1 = ok1 && (d[r] == refD(l15, q * 4 + r));
  }
  return __all(ok0) ? 0 : (__all(ok1) ? 1 : 2);
}

// ---- K0: dtype sniff ----
__global__ void sniff_kernel(const u32* __restrict__ xw) {
  int i = threadIdx.x;  // 64 threads
  u32 e = (xw[i] >> 7) & 0xFFu;
  unsigned long long b = __ballot(e >= 110u && e <= 135u);
  if (i == 0) g_isbf = (__popcll(b) >= 48) ? 1 : 0;
}

// ---- K1: zero replicas + fp32 x (xcd-replicated) + both weight forms ----
__global__ void prep_kernel(const void* __restrict__ x, const void* __restrict__ w_hid) {
  int t = blockIdx.x * blockDim.x + threadIdx.x;   // 1.6M threads
  int isbf = g_isbf;
  if (t < NREP * N_NODES) {
    g_agg[t] = 0.f;
    int qd = t / N_NODES;
    int node = t - qd * N_NODES;
    g_xf8[t] = ldf(x, node, isbf);
  }
  if (t < 6 * HID * HID) g_wf[t] = ldf(w_hid, t, isbf);
  if (t < 6 * PL_ELEMS) {
    int l = t / PL_ELEMS;
    int r = t - l * PL_ELEMS;
    int tile = r / TILE_ELEMS;
    int r2 = r - tile * TILE_ELEMS;
    int ks = r2 >> 9;              // 512 elems per (tile,ks) subtile
    int r3 = r2 & 511;
    int ln = r3 >> 3;              // lane 0..63
    int j  = r3 & 7;
    int q  = ln >> 4;
    int l15 = ln & 15;
    int n = tile * 16 + l15;
    int k = ks * 32 + q * 8 + j;
    float v = (n < HID && k < HID) ? ldf(w_hid, (l * HID + k) * HID + n, isbf) : 0.f;
    g_wph[t] = (_Float16)v;
  }
}

// ---- K2: edge scatter-add; 4 edges/thread (2x waves for latency hiding),
// XCD-local replica for BOTH the gather (g_xf8) and the atomic (g_agg). ----
__global__ void scatter_kernel(const int* __restrict__ ei) {
  int t = blockIdx.x * blockDim.x + threadIdx.x;   // 1.6M threads
  int e = t * 4;
  int xcc;
  asm volatile("s_getreg_b32 %0, hwreg(HW_REG_XCC_ID)" : "=s"(xcc));
  xcc &= (NREP - 1);
  const float* xf = g_xf8 + (size_t)xcc * N_NODES;
  float* agg = g_agg + (size_t)xcc * N_NODES;
  bool is64 = ((ei[1] | ei[3] | ei[5] | ei[7]) == 0);
  int s[4], d[4];
  if (is64) {
    int4 a0 = *(const int4*)(ei + 2 * e);
    int4 a1 = *(const int4*)(ei + 2 * e + 4);
    int4 b0 = *(const int4*)(ei + 2 * N_EDGES + 2 * e);
    int4 b1 = *(const int4*)(ei + 2 * N_EDGES + 2 * e + 4);
    s[0] = a0.x; s[1] = a0.z; s[2] = a1.x; s[3] = a1.z;
    d[0] = b0.x; d[1] = b0.z; d[2] = b1.x; d[3] = b1.z;
  } else {
    int4 a = *(const int4*)(ei + e);
    int4 b = *(const int4*)(ei + N_EDGES + e);
    s[0] = a.x; s[1] = a.y; s[2] = a.z; s[3] = a.w;
    d[0] = b.x; d[1] = b.y; d[2] = b.z; d[3] = b.w;
  }
  float v[4];
#pragma unroll
  for (int i = 0; i < 4; ++i) v[i] = xf[s[i]];
#pragma unroll
  for (int i = 0; i < 4; ++i) {
    float* p = &agg[d[i]];
    asm volatile("global_atomic_add_f32 %0, %1, off" :: "v"(p), "v"(v[i]) : "memory");
  }
}

// ---- K3: fused MLP. MT=64, 256 thr / 4 waves = 2 bands(32 rows) x 2 cgs,
// 4 blocks/CU (50% occ). B-fragments stream GLOBAL->REGISTER from packed
// g_wph (L2-resident, coalesced 1KB/wave-instr, compiler-pipelined vmcnt) --
// NO weight staging, NO staging barriers, NO vmcnt(0) drains. Only act lives
// in LDS. 2 barriers/layer. A-frags reg-cached per K-half (VGPR<=128).
__global__ __launch_bounds__(256, 4) void mlp_kernel(
    const void* __restrict__ w_rel, const void* __restrict__ b_rel, const void* __restrict__ w_root,
    const void* __restrict__ w_in, const void* __restrict__ b_in,
    const void* __restrict__ b_hid, const void* __restrict__ w_out, const void* __restrict__ b_out,
    void* __restrict__ out) {
  extern __shared__ char smem[];
  _Float16* act = (_Float16*)smem;
  float* h0s = (float*)(smem + LDS_H0S);

  const int tid = threadIdx.x;
  const int nb = blockIdx.x * MT;
  const int isbf = g_isbf;
  const int lane = tid & 63;
  const int wv = tid >> 6;          // 4 waves
  const int l15 = lane & 15;
  const int q = lane >> 4;
  const int band = wv >> 1;         // 2 bands x 32 rows
  const int cg = wv & 1;            // col group: cg0 tiles 0..6, cg1 tiles 7..12

  const int mode = mfma_selftest(l15, q);

  // GraphConv h0 (8 replicas summed)
  if (tid < MT) {
    int node = nb + tid;
    float a = 0.f;
#pragma unroll
    for (int r = 0; r < NREP; ++r) a += g_agg[(size_t)r * N_NODES + node];
    h0s[tid] = a * ldf(w_rel, 0, isbf) + ldf(b_rel, 0, isbf) +
               g_xf8[node] * ldf(w_root, 0, isbf);
  }
  __syncthreads();

  if (mode < 2) {
    // Input layer (vectorized): act[m][0..231], cols >= HID zeroed
    for (int u = tid; u < MT * 29; u += 256) {
      int m = u / 29, g = u - m * 29;
      float h0v = h0s[m];
      f16x8 pv;
#pragma unroll
      for (int jj = 0; jj < 8; ++jj) {
        int col = g * 8 + jj;
        float v = 0.f;
        if (col < HID) v = fmaxf(h0v * ldf(w_in, col, isbf) + ldf(b_in, col, isbf), 0.f);
        pv[jj] = (_Float16)v;
      }
      *(f16x8*)(act + m * ASTR + g * 8) = pv;
    }
    __syncthreads();

    const _Float16* ap0 = act + (band * 32 + l15) * ASTR + q * 8;   // row-tile 0
    const _Float16* ap1 = ap0 + 16 * ASTR;                          // row-tile 1
    const int tbase = cg ? 7 : 0;

    for (int l = 0; l < 6; ++l) {
      f32x4 acc[2][7];
#pragma unroll
      for (int rt = 0; rt < 2; ++rt)
#pragma unroll
        for (int n = 0; n < 7; ++n) acc[rt][n] = (f32x4){0.f, 0.f, 0.f, 0.f};

      const _Float16* gb = g_wph + (size_t)(l * 13 + tbase) * TILE_ELEMS + lane * 8;

      // ---- K-half 0: ks 0..3 (A-frags cached in 8 f16x8 = 32 VGPR) ----
      {
        f16x8 af0[4], af1[4];
#pragma unroll
        for (int k2 = 0; k2 < 4; ++k2) {
          af0[k2] = *(const f16x8*)(ap0 + k2 * 32);
          af1[k2] = *(const f16x8*)(ap1 + k2 * 32);
        }
        if (cg == 0) {
#pragma unroll
          for (int t = 0; t < 7; ++t) {
            const _Float16* gt_ = gb + t * TILE_ELEMS;
#pragma unroll
            for (int k2 = 0; k2 < 4; ++k2) {
              f16x8 b = *(const f16x8*)(gt_ + k2 * 512);
              acc[0][t] = __builtin_amdgcn_mfma_f32_16x16x32_f16(af0[k2], b, acc[0][t], 0, 0, 0);
              acc[1][t] = __builtin_amdgcn_mfma_f32_16x16x32_f16(af1[k2], b, acc[1][t], 0, 0, 0);
            }
          }
        } else {
#pragma unroll
          for (int t = 0; t < 6; ++t) {
            const _Float16* gt_ = gb + t * TILE_ELEMS;
#pragma unroll
            for (int k2 = 0; k2 < 4; ++k2) {
              f16x8 b = *(const f16x8*)(gt_ + k2 * 512);
              acc[0][t] = __builtin_amdgcn_mfma_f32_16x16x32_f16(af0[k2], b, acc[0][t], 0, 0, 0);
              acc[1][t] = __builtin_amdgcn_mfma_f32_16x16x32_f16(af1[k2], b, acc[1][t], 0, 0, 0);
            }
          }
        }
      }
      // ---- K-half 1: ks 4..6 ----
      {
        f16x8 af0[3], af1[3];
#pragma unroll
        for (int k2 = 0; k2 < 3; ++k2) {
          af0[k2] = *(const f16x8*)(ap0 + (4 + k2) * 32);
          af1[k2] = *(const f16x8*)(ap1 + (4 + k2) * 32);
        }
        if (cg == 0) {
#pragma unroll
          for (int t = 0; t < 7; ++t) {
            const _Float16* gt_ = gb + t * TILE_ELEMS + 4 * 512;
#pragma unroll
            for (int k2 = 0; k2 < 3; ++k2) {
              f16x8 b = *(const f16x8*)(gt_ + k2 * 512);
              acc[0][t] = __builtin_amdgcn_mfma_f32_16x16x32_f16(af0[k2], b, acc[0][t], 0, 0, 0);
              acc[1][t] = __builtin_amdgcn_mfma_f32_16x16x32_f16(af1[k2], b, acc[1][t], 0, 0, 0);
            }
          }
        } else {
#pragma unroll
          for (int t = 0; t < 6; ++t) {
            const _Float16* gt_ = gb + t * TILE_ELEMS + 4 * 512;
#pragma unroll
            for (int k2 = 0; k2 < 3; ++k2) {
              f16x8 b = *(const f16x8*)(gt_ + k2 * 512);
              acc[0][t] = __builtin_amdgcn_mfma_f32_16x16x32_f16(af0[k2], b, acc[0][t], 0, 0, 0);
              acc[1][t] = __builtin_amdgcn_mfma_f32_16x16x32_f16(af1[k2], b, acc[1][t], 0, 0, 0);
            }
          }
        }
      }

      __syncthreads();  // all A-reads done before in-place act writes

      // epilogue: bias + relu, in-place fp16 (all acc indices literal)
      if (cg == 0) {
#pragma unroll
        for (int rt = 0; rt < 2; ++rt)
#pragma unroll
          for (int i = 0; i < 7; ++i) {
            const int ctile = i * 16;
#pragma unroll
            for (int r = 0; r < 4; ++r) {
              int rr = (mode == 0) ? (q * 4 + r) : l15;
              int cc = (mode == 0) ? l15 : (q * 4 + r);
              int row = band * 32 + rt * 16 + rr, col = ctile + cc;
              float v = acc[rt][i][r] + ((col < HID) ? ldf(b_hid, l * HID + col, isbf) : 0.f);
              act[row * ASTR + col] = (_Float16)fmaxf(v, 0.f);
            }
          }
      } else {
#pragma unroll
        for (int rt = 0; rt < 2; ++rt)
#pragma unroll
          for (int i = 0; i < 6; ++i) {
            const int ctile = (7 + i) * 16;
#pragma unroll
            for (int r = 0; r < 4; ++r) {
              int rr = (mode == 0) ? (q * 4 + r) : l15;
              int cc = (mode == 0) ? l15 : (q * 4 + r);
              int row = band * 32 + rt * 16 + rr, col = ctile + cc;
              float v = acc[rt][i][r] + ((col < HID) ? ldf(b_hid, l * HID + col, isbf) : 0.f);
              act[row * ASTR + col] = (_Float16)fmaxf(v, 0.f);
            }
          }
      }
      __syncthreads();  // writes visible before next layer's A-reads
    }

    // Output layer: 4 threads/row x 50 cols
    {
      int m = tid >> 2, c = tid & 3;
      const _Float16* ar = act + m * ASTR;
      float s = 0.f;
#pragma unroll
      for (int j = c * 50; j < c * 50 + 50; ++j)
        s += (float)ar[j] * ldf(w_out, j, isbf);
      s += __shfl_down(s, 2);
      s += __shfl_down(s, 1);
      if (c == 0) {
        float logit = s + ldf(b_out, 0, isbf);
        float o = 1.f / (1.f + __expf(-logit));
        if (isbf) ((u16*)out)[nb + m] = f2bf(o);
        else ((float*)out)[nb + m] = o;
      }
    }
  } else {
    // ---- VALU fallback (defensive; 4 passes of 16 rows) ----
    float(*fA)[201] = (float(*)[201])smem;                    // 16x201 fp32
    float(*fB)[201] = (float(*)[201])(smem + 16 * 201 * 4);
    float* h0f = (float*)(smem + 32 * 201 * 4);
    for (int p = 0; p < 4; ++p) {
      __syncthreads();
      if (tid < 16) {
        int node = nb + p * 16 + tid;
        float a = 0.f;
#pragma unroll
        for (int r = 0; r < NREP; ++r) a += g_agg[(size_t)r * N_NODES + node];
        h0f[tid] = a * ldf(w_rel, 0, isbf) + ldf(b_rel, 0, isbf) +
                   g_xf8[node] * ldf(w_root, 0, isbf);
      }
      __syncthreads();
      for (int i = tid; i < 16 * HID; i += 256) {
        int mm = i / HID, ff = i - mm * HID;
        float v = h0f[mm] * ldf(w_in, ff, isbf) + ldf(b_in, ff, isbf);
        fA[mm][ff] = v > 0.f ? v : 0.f;
      }
      __syncthreads();
      const int m = tid >> 4, c = tid & 15;
      float(*ain)[201] = fA;
      float(*aout)[201] = fB;
      for (int l = 0; l < 6; ++l) {
        float acc[13];
#pragma unroll
        for (int jj = 0; jj < 13; ++jj) {
          int j = c * 13 + jj;
          acc[jj] = (j < HID) ? ldf(b_hid, l * HID + j, isbf) : 0.f;
        }
        const float* wl = g_wf + l * HID * HID;
        for (int k = 0; k < HID; ++k) {
          float a = ain[m][k];
          const float* wr = wl + k * HID;
#pragma unroll
          for (int jj = 0; jj < 13; ++jj) {
            int j = c * 13 + jj;
            if (j < HID) acc[jj] = fmaf(a, wr[j], acc[jj]);
          }
        }
        __syncthreads();
#pragma unroll
        for (int jj = 0; jj < 13; ++jj) {
          int j = c * 13 + jj;
          if (j < HID) aout[m][j] = fmaxf(acc[jj], 0.f);
        }
        float(*tsw)[201] = ain; ain = aout; aout = tsw;
        __syncthreads();
      }
      float s = 0.f;
      for (int j = c * 13; j < c * 13 + 13 && j < HID; ++j)
        s += ain[m][j] * ldf(w_out, j, isbf);
      s += __shfl_down(s, 8);
      s += __shfl_down(s, 4);
      s += __shfl_down(s, 2);
      s += __shfl_down(s, 1);
      int node = nb + p * 16 + m;
      if (c == 0) {
        float logit = s + ldf(b_out, 0, isbf);
        float o = 1.f / (1.f + __expf(-logit));
        if (isbf) ((u16*)out)[node] = f2bf(o);
        else ((float*)out)[node] = o;
      }
    }
  }
}

extern "C" void kernel_launch(void* const* d_in, const int* in_sizes, int n_in,
                              void* d_out, int out_size, void* d_ws, size_t ws_size,
                              hipStream_t stream) {
  const void* x      = d_in[0];
  const int* ei      = (const int*)d_in[1];
  const void* w_rel  = d_in[2];
  const void* b_rel  = d_in[3];
  const void* w_root = d_in[4];
  const void* w_in   = d_in[5];
  const void* b_in   = d_in[6];
  const void* w_hid  = d_in[7];
  const void* b_hid  = d_in[8];
  const void* w_out  = d_in[9];
  const void* b_out  = d_in[10];
  (void)d_ws; (void)ws_size; (void)in_sizes; (void)n_in; (void)out_size;

  sniff_kernel<<<1, 64, 0, stream>>>((const u32*)x);
  prep_kernel<<<(NREP * N_NODES + 255) / 256, 256, 0, stream>>>(x, w_hid);
  scatter_kernel<<<N_EDGES / 4 / 256, 256, 0, stream>>>(ei);
  mlp_kernel<<<N_NODES / MT, 256, LDS_TOTAL, stream>>>(
      w_rel, b_rel, w_root, w_in, b_in, b_hid, w_out, b_out, d_out);
}

// Round 4
// 773.900 us; speedup vs baseline: 1.6680x; 1.6680x over previous
//
#include <hip/hip_runtime.h>

#define N_NODES 200000
#define N_EDGES 6400000
#define HID 200
#define NREP 8                    // scatter accumulator replicas (one per XCD)
#define APITCH 208                // act row pitch (fp16) = 416 B, 16B-aligned
#define NSTRIP (N_NODES / 32)     // 6250 strips of 32 rows, exact
#define ACT_ELEMS (N_NODES * APITCH + 64)   // +64 pad for k-overflow reads

// Packed B layout (R2-verified): g_wph[l][tile 13][ks 7][lane 64][j 8] =
//   W^T[n = tile*16 + (lane&15)][k = ks*32 + (lane>>4)*8 + j], zero-padded.
// Per-wave B-frag = 1024 CONTIGUOUS bytes (conflict-free LDS, coalesced HBM).
#define TILE_ELEMS (7 * 512)
#define PL_ELEMS (13 * TILE_ELEMS)        // 46592 elems = 93184 B per layer
#define WCHUNKS (PL_ELEMS * 2 / 16)       // 5824 16-B staging chunks
#define LDS_BIAS (PL_ELEMS * 2)           // bias table after weights
#define LDSH_TOTAL (LDS_BIAS + 208 * 4)   // 94016 B -> 1 block/CU

typedef float f32x4 __attribute__((ext_vector_type(4)));
typedef _Float16 f16x8 __attribute__((ext_vector_type(8)));
typedef unsigned short u16;
typedef unsigned int u32;

__device__ __align__(16) float g_agg[NREP * N_NODES];
__device__ __align__(16) float g_xf8[NREP * N_NODES];    // fp32 x, per-XCD replica
__device__ __align__(16) float g_wf[6 * HID * HID];      // fp32 (VALU fallback)
__device__ __align__(16) _Float16 g_wph[6 * PL_ELEMS];   // fp16 packed W^T
__device__ __align__(16) float g_ev[N_EDGES];            // gathered x[src] values
__device__ __align__(16) _Float16 g_actA[ACT_ELEMS];     // activation ping
__device__ __align__(16) _Float16 g_actB[ACT_ELEMS];     // activation pong
__device__ int g_isbf;

__device__ __forceinline__ float bf2f(u16 u) {
  union { u32 i; float f; } v; v.i = ((u32)u) << 16; return v.f;
}
__device__ __forceinline__ u16 f2bf(float f) {  // RNE
  u32 i = __float_as_uint(f);
  return (u16)((i + 0x7FFFu + ((i >> 16) & 1u)) >> 16);
}
__device__ __forceinline__ float ldf(const void* p, int i, int isbf) {
  return isbf ? bf2f(((const u16*)p)[i]) : ((const float*)p)[i];
}
__device__ __forceinline__ void load_lds16(const void* g, void* l) {
  __builtin_amdgcn_global_load_lds(
      (const __attribute__((address_space(1))) u32*)g,
      (__attribute__((address_space(3))) u32*)l, 16, 0, 0);
}

// ---- rank-2 MFMA layout self-test (fp16), reference folded at compile time ----
constexpr int tf1(int m) { return (m & 3) + 1; }
constexpr int tf2(int m) { return ((m >> 2) & 3) + 2; }
constexpr int tg1(int k) { return (k & 7) + 1; }
constexpr int tg2(int k) { return ((k >> 3) & 3) + 1; }
constexpr int tu1(int k) { return ((k * 3) & 7) + 1; }
constexpr int tu2(int k) { return ((k >> 2) & 3) + 2; }
constexpr int tw1(int n) { return ((n * 5) & 7) + 1; }
constexpr int tw2(int n) { return ((n >> 2) & 3) + 1; }
constexpr int calcS(int i, int j) {
  int s = 0;
  for (int k = 0; k < 32; ++k)
    s += (i ? tg2(k) : tg1(k)) * (j ? tu2(k) : tu1(k));
  return s;
}
__device__ __forceinline__ float refD(int m, int n) {
  constexpr int S11 = calcS(0, 0), S12 = calcS(0, 1), S21 = calcS(1, 0), S22 = calcS(1, 1);
  return (float)(tf1(m) * tw1(n) * S11 + tf1(m) * tw2(n) * S12 +
                 tf2(m) * tw1(n) * S21 + tf2(m) * tw2(n) * S22);
}
__device__ int mfma_selftest(int l15, int q) {
  f16x8 av, bv;
#pragma unroll
  for (int j = 0; j < 8; ++j) {
    int k = q * 8 + j;
    av[j] = (_Float16)(float)(tf1(l15) * tg1(k) + tf2(l15) * tg2(k));
    bv[j] = (_Float16)(float)(tu1(k) * tw1(l15) + tu2(k) * tw2(l15));
  }
  f32x4 d = __builtin_amdgcn_mfma_f32_16x16x32_f16(av, bv, (f32x4){0.f, 0.f, 0.f, 0.f}, 0, 0, 0);
  bool ok0 = true, ok1 = true;
#pragma unroll
  for (int r = 0; r < 4; ++r) {
    ok0 = ok0 && (d[r] == refD(q * 4 + r, l15));
    ok1 = ok1 && (d[r] == refD(l15, q * 4 + r));
  }
  return __all(ok0) ? 0 : (__all(ok1) ? 1 : 2);
}

// ---- K0: dtype sniff ----
__global__ void sniff_kernel(const u32* __restrict__ xw) {
  int i = threadIdx.x;  // 64 threads
  u32 e = (xw[i] >> 7) & 0xFFu;
  unsigned long long b = __ballot(e >= 110u && e <= 135u);
  if (i == 0) g_isbf = (__popcll(b) >= 48) ? 1 : 0;
}

// ---- K1: zero replicas + replicate x + both weight forms + act pads ----
__global__ void prep_kernel(const void* __restrict__ x, const void* __restrict__ w_hid) {
  int t = blockIdx.x * blockDim.x + threadIdx.x;   // 1.6M threads
  int isbf = g_isbf;
  if (t < NREP * N_NODES) {
    g_agg[t] = 0.f;
    int qd = t / N_NODES;
    int node = t - qd * N_NODES;
    g_xf8[t] = ldf(x, node, isbf);
  }
  if (t < 6 * HID * HID) g_wf[t] = ldf(w_hid, t, isbf);
  if (t < 6 * PL_ELEMS) {
    int l = t / PL_ELEMS;
    int r = t - l * PL_ELEMS;
    int tile = r / TILE_ELEMS;
    int r2 = r - tile * TILE_ELEMS;
    int ks = r2 >> 9;
    int r3 = r2 & 511;
    int ln = r3 >> 3;
    int j  = r3 & 7;
    int q  = ln >> 4;
    int l15 = ln & 15;
    int n = tile * 16 + l15;
    int k = ks * 32 + q * 8 + j;
    float v = (n < HID && k < HID) ? ldf(w_hid, (l * HID + k) * HID + n, isbf) : 0.f;
    g_wph[t] = (_Float16)v;
  }
  if (t < 64) {  // zero act tail pads (k-overflow reads hit these; must not be NaN)
    g_actA[(size_t)N_NODES * APITCH + t] = (_Float16)0.f;
    g_actB[(size_t)N_NODES * APITCH + t] = (_Float16)0.f;
  }
}

// ---- K2a: gather x[src] -> linear g_ev (diagnostic split: isolates random-
// gather cost from atomic-RMW cost; each phase now large enough to profile) ----
__global__ void gather_kernel(const int* __restrict__ ei) {
  int t = blockIdx.x * blockDim.x + threadIdx.x;   // 800K threads
  int e = t * 8;
  int xcc;
  asm volatile("s_getreg_b32 %0, hwreg(HW_REG_XCC_ID)" : "=s"(xcc));
  const float* xf = g_xf8 + (size_t)(xcc & (NREP - 1)) * N_NODES;
  bool is64 = ((ei[1] | ei[3] | ei[5] | ei[7]) == 0);
  int s[8];
  if (is64) {
#pragma unroll
    for (int i = 0; i < 4; ++i) {
      int4 a = *(const int4*)(ei + 2 * e + 4 * i);
      s[2 * i] = a.x; s[2 * i + 1] = a.z;
    }
  } else {
#pragma unroll
    for (int i = 0; i < 2; ++i) {
      int4 a = *(const int4*)(ei + e + 4 * i);
      s[4 * i] = a.x; s[4 * i + 1] = a.y; s[4 * i + 2] = a.z; s[4 * i + 3] = a.w;
    }
  }
  float v[8];
#pragma unroll
  for (int i = 0; i < 8; ++i) v[i] = xf[s[i]];
  *(float4*)(g_ev + e) = (float4){v[0], v[1], v[2], v[3]};
  *(float4*)(g_ev + e + 4) = (float4){v[4], v[5], v[6], v[7]};
}

// ---- K2b: linear g_ev + dst -> XCD-local atomic add ----
__global__ void apply_kernel(const int* __restrict__ ei) {
  int t = blockIdx.x * blockDim.x + threadIdx.x;   // 800K threads
  int e = t * 8;
  int xcc;
  asm volatile("s_getreg_b32 %0, hwreg(HW_REG_XCC_ID)" : "=s"(xcc));
  float* agg = g_agg + (size_t)(xcc & (NREP - 1)) * N_NODES;
  bool is64 = ((ei[1] | ei[3] | ei[5] | ei[7]) == 0);
  int d[8];
  if (is64) {
#pragma unroll
    for (int i = 0; i < 4; ++i) {
      int4 b = *(const int4*)(ei + 2 * N_EDGES + 2 * e + 4 * i);
      d[2 * i] = b.x; d[2 * i + 1] = b.z;
    }
  } else {
#pragma unroll
    for (int i = 0; i < 2; ++i) {
      int4 b = *(const int4*)(ei + N_EDGES + e + 4 * i);
      d[4 * i] = b.x; d[4 * i + 1] = b.y; d[4 * i + 2] = b.z; d[4 * i + 3] = b.w;
    }
  }
  float4 v0 = *(const float4*)(g_ev + e);
  float4 v1 = *(const float4*)(g_ev + e + 4);
  float v[8] = {v0.x, v0.y, v0.z, v0.w, v1.x, v1.y, v1.z, v1.w};
#pragma unroll
  for (int i = 0; i < 8; ++i) {
    float* p = &agg[d[i]];
    asm volatile("global_atomic_add_f32 %0, %1, off" :: "v"(p), "v"(v[i]) : "memory");
  }
}

// ---- K3: GraphConv + input layer -> g_actA ----
__global__ void input_kernel(const void* __restrict__ w_rel, const void* __restrict__ b_rel,
                             const void* __restrict__ w_root, const void* __restrict__ w_in,
                             const void* __restrict__ b_in) {
  __shared__ float sw[HID], sb[HID];
  int tid = threadIdx.x;
  int isbf = g_isbf;
  for (int i = tid; i < HID; i += 512) { sw[i] = ldf(w_in, i, isbf); sb[i] = ldf(b_in, i, isbf); }
  __syncthreads();
  int node = blockIdx.x * 512 + tid;
  if (node >= N_NODES) return;
  float a = 0.f;
#pragma unroll
  for (int r = 0; r < NREP; ++r) a += g_agg[(size_t)r * N_NODES + node];
  float h0 = a * ldf(w_rel, 0, isbf) + ldf(b_rel, 0, isbf) +
             g_xf8[node] * ldf(w_root, 0, isbf);
  _Float16* ar = g_actA + (size_t)node * APITCH;
#pragma unroll
  for (int g = 0; g < 26; ++g) {
    f16x8 pv;
#pragma unroll
    for (int j = 0; j < 8; ++j) {
      int col = g * 8 + j;
      float v = (col < HID) ? fmaxf(h0 * sw[col] + sb[col], 0.f) : 0.f;
      pv[j] = (_Float16)v;
    }
    *(f16x8*)(ar + g * 8) = pv;
  }
}

// ---- K4 x6: one hidden layer. Weights LDS-resident (staged ONCE per block),
// 8 waves x 32-row strips, ZERO barriers in the strip loop. A: global->reg
// (L3-resident act arrays). B: contiguous conflict-free 1KB LDS reads, each
// feeding 2 MFMAs (2 row-tiles). acc/af indices all literal (rule 20);
// launch_bounds(512,2) -> 256-VGPR cap, no spill (est ~210). ----
__global__ __launch_bounds__(512, 2) void layer_kernel(
    int l, int dir, const void* __restrict__ b_hid) {
  extern __shared__ char smem[];
  _Float16* wl = (_Float16*)smem;
  float* biasl = (float*)(smem + LDS_BIAS);
  const _Float16* ain = dir ? g_actB : g_actA;
  _Float16* aout = dir ? g_actA : g_actB;

  const int tid = threadIdx.x;
  const int isbf = g_isbf;
  const int lane = tid & 63;
  const int wv = tid >> 6;
  const int l15 = lane & 15;
  const int q = lane >> 4;
  const int mode = mfma_selftest(l15, q);

  {  // stage packed layer weights + bias, once
    const _Float16* wg = g_wph + (size_t)l * PL_ELEMS;
    for (int c = tid; c < WCHUNKS; c += 512) load_lds16(wg + c * 8, wl + c * 8);
  }
  for (int i = tid; i < 208; i += 512)
    biasl[i] = (i < HID) ? ldf(b_hid, l * HID + i, isbf) : 0.f;
  __syncthreads();   // drains staging; the ONLY barrier in this kernel

  const int wgid = blockIdx.x * 8 + wv;   // 2048 waves

  if (mode < 2) {
    float bias_c[13];
#pragma unroll
    for (int t = 0; t < 13; ++t) bias_c[t] = biasl[t * 16 + l15];

    for (int s = wgid; s < NSTRIP; s += 2048) {
      const _Float16* ar0 = ain + (size_t)(s * 32 + l15) * APITCH + q * 8;
      const _Float16* ar1 = ar0 + 16 * APITCH;
      f16x8 af0[7], af1[7];
#pragma unroll
      for (int ks = 0; ks < 7; ++ks) {
        af0[ks] = *(const f16x8*)(ar0 + ks * 32);
        af1[ks] = *(const f16x8*)(ar1 + ks * 32);
      }
      f32x4 acc[2][13];
#pragma unroll
      for (int rt = 0; rt < 2; ++rt)
#pragma unroll
        for (int t = 0; t < 13; ++t) acc[rt][t] = (f32x4){0.f, 0.f, 0.f, 0.f};

#pragma unroll
      for (int t = 0; t < 13; ++t)
#pragma unroll
        for (int ks = 0; ks < 7; ++ks) {
          f16x8 b = *(const f16x8*)(wl + ((t * 7 + ks) << 9) + lane * 8);
          acc[0][t] = __builtin_amdgcn_mfma_f32_16x16x32_f16(af0[ks], b, acc[0][t], 0, 0, 0);
          acc[1][t] = __builtin_amdgcn_mfma_f32_16x16x32_f16(af1[ks], b, acc[1][t], 0, 0, 0);
        }

      // epilogue: bias + relu + fp16 store (104 scalar stores)
#pragma unroll
      for (int rt = 0; rt < 2; ++rt)
#pragma unroll
        for (int t = 0; t < 13; ++t)
#pragma unroll
          for (int r = 0; r < 4; ++r) {
            int rr = (mode == 0) ? (q * 4 + r) : l15;
            int cc = (mode == 0) ? l15 : (q * 4 + r);
            int row = s * 32 + rt * 16 + rr;
            int col = t * 16 + cc;
            float bv = (mode == 0) ? bias_c[t] : biasl[col];
            float v = acc[rt][t][r] + bv;
            aout[(size_t)row * APITCH + col] = (_Float16)fmaxf(v, 0.f);
          }
    }
  } else {
    // ---- defensive VALU fallback (never taken on gfx950; correctness only) ----
    for (int s = wgid; s < NSTRIP; s += 2048) {
      int row = s * 32 + (lane & 31);
      const _Float16* ar = ain + (size_t)row * APITCH;
      int j0b = (lane >> 5) * 100;
      for (int j0 = j0b; j0 < j0b + 100; j0 += 2) {
        float a0 = biasl[j0], a1 = biasl[j0 + 1];
        for (int k = 0; k < HID; ++k) {
          float av = (float)ar[k];
          a0 += av * g_wf[(l * HID + k) * HID + j0];
          a1 += av * g_wf[(l * HID + k) * HID + j0 + 1];
        }
        aout[(size_t)row * APITCH + j0] = (_Float16)fmaxf(a0, 0.f);
        aout[(size_t)row * APITCH + j0 + 1] = (_Float16)fmaxf(a1, 0.f);
      }
      if (lane >> 5) {
#pragma unroll
        for (int j = HID; j < APITCH; ++j) aout[(size_t)row * APITCH + j] = (_Float16)0.f;
      }
    }
  }
}

// ---- K5: output layer + sigmoid ----
__global__ void output_kernel(const void* __restrict__ w_out, const void* __restrict__ b_out,
                              void* __restrict__ out) {
  __shared__ float swo[HID];
  int tid = threadIdx.x;
  int isbf = g_isbf;
  for (int i = tid; i < HID; i += 512) swo[i] = ldf(w_out, i, isbf);
  __syncthreads();
  int m = blockIdx.x * 64 + (tid >> 3), c = tid & 7;
  if (m >= N_NODES) return;
  const _Float16* ar = g_actA + (size_t)m * APITCH;
  float s = 0.f;
#pragma unroll
  for (int j = c * 25; j < c * 25 + 25; ++j) s += (float)ar[j] * swo[j];
  s += __shfl_down(s, 4);
  s += __shfl_down(s, 2);
  s += __shfl_down(s, 1);
  if (c == 0) {
    float logit = s + ldf(b_out, 0, isbf);
    float o = 1.f / (1.f + __expf(-logit));
    if (isbf) ((u16*)out)[m] = f2bf(o);
    else ((float*)out)[m] = o;
  }
}

extern "C" void kernel_launch(void* const* d_in, const int* in_sizes, int n_in,
                              void* d_out, int out_size, void* d_ws, size_t ws_size,
                              hipStream_t stream) {
  const void* x      = d_in[0];
  const int* ei      = (const int*)d_in[1];
  const void* w_rel  = d_in[2];
  const void* b_rel  = d_in[3];
  const void* w_root = d_in[4];
  const void* w_in   = d_in[5];
  const void* b_in   = d_in[6];
  const void* w_hid  = d_in[7];
  const void* b_hid  = d_in[8];
  const void* w_out  = d_in[9];
  const void* b_out  = d_in[10];
  (void)d_ws; (void)ws_size; (void)in_sizes; (void)n_in; (void)out_size;

  sniff_kernel<<<1, 64, 0, stream>>>((const u32*)x);
  prep_kernel<<<(NREP * N_NODES + 255) / 256, 256, 0, stream>>>(x, w_hid);
  gather_kernel<<<N_EDGES / 8 / 256, 256, 0, stream>>>(ei);
  apply_kernel<<<N_EDGES / 8 / 256, 256, 0, stream>>>(ei);
  input_kernel<<<(N_NODES + 511) / 512, 512, 0, stream>>>(w_rel, b_rel, w_root, w_in, b_in);
  for (int l = 0; l < 6; ++l)
    layer_kernel<<<256, 512, LDSH_TOTAL, stream>>>(l, l & 1, b_hid);
  output_kernel<<<N_NODES / 64, 512, 0, stream>>>(w_out, b_out, d_out);
}